// Round 1
// baseline (4203.851 us; speedup 1.0000x reference)
//
#include <hip/hip_runtime.h>
#include <hip/hip_bf16.h>
#include <math.h>

#define B_ 8
#define H_ 8
#define T_ 8192
#define D_ 64
#define NC_ 128
#define WSZ_ 64
#define T2_ (2*T_)
#define BH_ (B_*H_)
#define CHUNK_BH 8
#define NCHUNK (BH_/CHUNK_BH)

// workspace layout (bytes)
#define OFF_AUX   0
#define OFF_DEN   4096
#define OFF_QIDX  (OFF_DEN  + BH_*T_*4)          // 2,101,248
#define OFF_KIDX  (OFF_QIDX + BH_*NC_*WSZ_*4)    // +2 MiB
#define OFF_DISTS (OFF_KIDX + BH_*NC_*WSZ_*4)    // +2 MiB
// dists: CHUNK_BH*NC_*T2_ floats = 64 MiB  -> total ~73.4 MB

// ---------------------------------------------------------------------------
// K1: dists (transposed) + argmax + aux partial
// block: 256 threads, handles 128 tokens x 128 clusters for one (bh)
// grid: (T2/128, CHUNK_BH)
// ---------------------------------------------------------------------------
__global__ __launch_bounds__(256)
void k_dists(const float* __restrict__ q, const float* __restrict__ k,
             const float* __restrict__ means, float* __restrict__ dists,
             float* __restrict__ aux, int bh_base)
{
    __shared__ float xs[128*64];      // 32 KB normalized tokens
    __shared__ float dtile[32*129];   // 16.5 KB dist sub-tile (padded)
    __shared__ float rno[128];
    __shared__ float ar[4];

    const int tid = threadIdx.x;
    const int bhl = blockIdx.y;
    const int bh  = bh_base + bhl;
    const int h   = bh % H_;
    const int t0  = blockIdx.x * 128;
    const float* mh = means + (size_t)h * NC_ * D_;

    // ---- load 128 token rows, compute sumsq per token (1 token per wave/iter)
    {
        const int lane = tid & 63;
        const int wtok = tid >> 6;  // wave id 0..3
        for (int it = 0; it < 32; ++it) {
            int tl = it*4 + wtok;
            int gt = t0 + tl;
            const float* src = (gt < T_)
                ? (q + ((size_t)bh*T_ + gt)*D_)
                : (k + ((size_t)bh*T_ + (gt - T_))*D_);
            float vv = src[lane];
            xs[tl*64 + lane] = vv;
            float s = vv*vv;
            #pragma unroll
            for (int off = 32; off > 0; off >>= 1) s += __shfl_xor(s, off);
            if (lane == 0) rno[tl] = s;
        }
    }
    __syncthreads();
    if (tid < 128) rno[tid] = fmaxf(sqrtf(rno[tid]), 1e-12f);
    __syncthreads();
    for (int it = 0; it < 32; ++it) {
        int idx = it*256 + tid;
        xs[idx] = xs[idx] / rno[idx >> 6];
    }
    __syncthreads();

    // ---- dists: thread handles clusters (cbase+cl, cbase+cl+16) x 8 tokens
    float best = -1e30f; int bestc = 0;
    const int cl = tid & 15;
    const int tg = tid >> 4;        // 0..15, tokens tg*8 .. tg*8+7
    for (int cbase = 0; cbase < NC_; cbase += 32) {
        const float4* m0p = (const float4*)(mh + (size_t)(cbase + cl)*D_);
        const float4* m1p = (const float4*)(mh + (size_t)(cbase + cl + 16)*D_);
        float acc0[8], acc1[8];
        #pragma unroll
        for (int t = 0; t < 8; ++t) { acc0[t] = 0.f; acc1[t] = 0.f; }
        #pragma unroll 4
        for (int dc = 0; dc < 16; ++dc) {
            float4 m0 = m0p[dc];
            float4 m1 = m1p[dc];
            #pragma unroll
            for (int t = 0; t < 8; ++t) {
                float4 xv = *(const float4*)&xs[(tg*8 + t)*64 + dc*4];
                acc0[t] = fmaf(xv.w, m0.w, fmaf(xv.z, m0.z, fmaf(xv.y, m0.y, fmaf(xv.x, m0.x, acc0[t]))));
                acc1[t] = fmaf(xv.w, m1.w, fmaf(xv.z, m1.z, fmaf(xv.y, m1.y, fmaf(xv.x, m1.x, acc1[t]))));
            }
        }
        #pragma unroll
        for (int t = 0; t < 8; ++t) {
            dtile[cl*129 + tg*8 + t]      = acc0[t];
            dtile[(cl+16)*129 + tg*8 + t] = acc1[t];
        }
        __syncthreads();
        if (tid < 128) {
            #pragma unroll 4
            for (int c = 0; c < 32; ++c) {
                float vv = dtile[c*129 + tid];
                if (vv > best) { best = vv; bestc = cbase + c; }
            }
        }
        // coalesced flush of 32x128 tile
        {
            const int fc = tid >> 3;          // 0..31
            const int ft = (tid & 7) * 16;    // 0..112
            float* gout = dists + ((size_t)(bhl*NC_ + cbase + fc))*T2_ + t0 + ft;
            #pragma unroll
            for (int j4 = 0; j4 < 4; ++j4) {
                float4 vv;
                vv.x = dtile[fc*129 + ft + j4*4 + 0];
                vv.y = dtile[fc*129 + ft + j4*4 + 1];
                vv.z = dtile[fc*129 + ft + j4*4 + 2];
                vv.w = dtile[fc*129 + ft + j4*4 + 3];
                *(float4*)(gout + j4*4) = vv;
            }
        }
        __syncthreads();
    }

    // ---- aux: sum over d of (xn - means[h][bestc])^2, token per thread
    float asum = 0.f;
    if (tid < 128) {
        const float* mr = mh + (size_t)bestc*D_;
        float s = 0.f;
        for (int j = 0; j < 64; ++j) {
            float dfr = xs[tid*64 + j] - mr[j];
            s = fmaf(dfr, dfr, s);
        }
        asum = s;
    }
    #pragma unroll
    for (int off = 32; off > 0; off >>= 1) asum += __shfl_xor(asum, off);
    if ((tid & 63) == 0) ar[tid >> 6] = asum;
    __syncthreads();
    if (tid == 0) atomicAdd(aux, ar[0] + ar[1] + ar[2] + ar[3]);
}

// ---------------------------------------------------------------------------
// K2: top-64 of 8192 via LDS radix select (exact JAX tie-breaking)
// grid: (NC, CHUNK_BH, 2)   block: 256
// ---------------------------------------------------------------------------
__global__ __launch_bounds__(256)
void k_topk(const float* __restrict__ dists, int* __restrict__ qidx,
            int* __restrict__ kidx, int bh_base)
{
    __shared__ unsigned su[T_];     // 32 KB
    __shared__ unsigned hist[256];
    __shared__ int eqbuf[256];
    __shared__ int sh[4];           // 0:k  1:bin  2:cnt_gt  3:cnt_eq

    const int tid   = threadIdx.x;
    const int c     = blockIdx.x;
    const int bhl   = blockIdx.y;
    const int which = blockIdx.z;
    const float* row = dists + ((size_t)(bhl*NC_ + c))*T2_ + (size_t)which*T_;

    for (int it = 0; it < 32; ++it) {
        int i = it*256 + tid;
        unsigned bits = __float_as_uint(row[i]);
        su[i] = (bits & 0x80000000u) ? ~bits : (bits | 0x80000000u);
    }
    if (tid == 0) sh[0] = WSZ_;
    __syncthreads();

    unsigned prefix = 0, mask = 0;
    for (int shift = 24; shift >= 0; shift -= 8) {
        hist[tid] = 0;
        __syncthreads();
        for (int it = 0; it < 32; ++it) {
            unsigned u = su[it*256 + tid];
            if ((u & mask) == prefix) atomicAdd(&hist[(u >> shift) & 255u], 1u);
        }
        __syncthreads();
        if (tid == 0) {
            int kk = sh[0];
            int b = 255;
            for (; b > 0; --b) {
                int cnt = (int)hist[b];
                if (kk - cnt <= 0) break;
                kk -= cnt;
            }
            sh[0] = kk; sh[1] = b;
        }
        __syncthreads();
        prefix |= ((unsigned)sh[1]) << shift;
        mask   |= 0xFFu << shift;
        __syncthreads();
    }
    const unsigned thr = prefix;
    const int needeq = sh[0];       // how many ==thr to take (lowest indices)
    if (tid == 0) { sh[2] = 0; sh[3] = 0; }
    __syncthreads();

    int* outp = (which ? kidx : qidx) + ((size_t)((bh_base + bhl)*NC_ + c))*WSZ_;
    for (int it = 0; it < 32; ++it) {
        int i = it*256 + tid;
        unsigned u = su[i];
        if (u > thr) {
            int p = atomicAdd(&sh[2], 1);
            outp[p] = i;
        } else if (u == thr) {
            int p = atomicAdd(&sh[3], 1);
            if (p < 256) eqbuf[p] = i;
        }
    }
    __syncthreads();
    if (tid == 0) {
        int G = sh[2];
        int E = sh[3] < 256 ? sh[3] : 256;
        for (int n = 0; n < needeq; ++n) {
            int mi = 0x7fffffff, mj = 0;
            for (int j = 0; j < E; ++j) {
                int vv = eqbuf[j];
                if (vv < mi) { mi = vv; mj = j; }
            }
            eqbuf[mj] = 0x7fffffff;
            outp[G + n] = mi;
        }
    }
}

// ---------------------------------------------------------------------------
// K3: per-cluster 64x64 attention + scatter-add
// grid: (NC, BH)  block: 256
// ---------------------------------------------------------------------------
__global__ __launch_bounds__(256)
void k_attn(const float* __restrict__ q, const float* __restrict__ k,
            const float* __restrict__ v, const int* __restrict__ qidx,
            const int* __restrict__ kidx, float* __restrict__ out,
            float* __restrict__ den)
{
    __shared__ float Qs[64*68];   // also holds P after softmax
    __shared__ float Ks[64*68];
    __shared__ float Vs[64*68];
    __shared__ int qi[64], ki[64];

    const int tid = threadIdx.x;
    const int c  = blockIdx.x;
    const int bh = blockIdx.y;
    const int* qp = qidx + ((size_t)(bh*NC_ + c))*WSZ_;
    const int* kp = kidx + ((size_t)(bh*NC_ + c))*WSZ_;
    if (tid < 64) { qi[tid] = qp[tid]; ki[tid] = kp[tid]; }
    __syncthreads();

    // gather Q,K,V rows (thread: row=tid>>2, 16-col segment)
    {
        const int row = tid >> 2, seg = (tid & 3) * 16;
        const float* qsrc = q + ((size_t)bh*T_ + qi[row])*D_ + seg;
        const float* ksrc = k + ((size_t)bh*T_ + ki[row])*D_ + seg;
        const float* vsrc = v + ((size_t)bh*T_ + ki[row])*D_ + seg;
        #pragma unroll
        for (int j4 = 0; j4 < 4; ++j4) {
            *(float4*)&Qs[row*68 + seg + j4*4] = ((const float4*)qsrc)[j4];
            *(float4*)&Ks[row*68 + seg + j4*4] = ((const float4*)ksrc)[j4];
            *(float4*)&Vs[row*68 + seg + j4*4] = ((const float4*)vsrc)[j4];
        }
    }
    __syncthreads();

    // S = Q K^T * 0.125 (thread: query si, 16 keys)
    const int si = tid >> 2;
    const int sj = (tid & 3) * 16;
    float sacc[16];
    #pragma unroll
    for (int jj = 0; jj < 16; ++jj) sacc[jj] = 0.f;
    for (int kk4 = 0; kk4 < 16; ++kk4) {
        float4 qv = *(const float4*)&Qs[si*68 + kk4*4];
        #pragma unroll
        for (int jj = 0; jj < 16; ++jj) {
            float4 kv = *(const float4*)&Ks[(sj + jj)*68 + kk4*4];
            sacc[jj] = fmaf(qv.w, kv.w, fmaf(qv.z, kv.z, fmaf(qv.y, kv.y, fmaf(qv.x, kv.x, sacc[jj]))));
        }
    }
    __syncthreads();   // all Qs reads done before P overwrite

    // softmax across the quad (4 threads own one row)
    float lmax = -1e30f;
    #pragma unroll
    for (int jj = 0; jj < 16; ++jj) lmax = fmaxf(lmax, sacc[jj]*0.125f);
    lmax = fmaxf(lmax, __shfl_xor(lmax, 1));
    lmax = fmaxf(lmax, __shfl_xor(lmax, 2));
    float ebuf[16];
    float lsum = 0.f;
    #pragma unroll
    for (int jj = 0; jj < 16; ++jj) {
        float e = expf(sacc[jj]*0.125f - lmax);
        ebuf[jj] = e; lsum += e;
    }
    lsum += __shfl_xor(lsum, 1);
    lsum += __shfl_xor(lsum, 2);
    const float rs = 1.0f / lsum;
    #pragma unroll
    for (int jj = 0; jj < 16; ++jj) Qs[si*68 + sj + jj] = ebuf[jj] * rs;
    __syncthreads();

    // O = P V (thread: row r, 16-wide d segment)
    const int r = tid >> 2, dg = (tid & 3) * 16;
    float oacc[16];
    #pragma unroll
    for (int dd = 0; dd < 16; ++dd) oacc[dd] = 0.f;
    for (int j = 0; j < 64; ++j) {
        float p = Qs[r*68 + j];
        #pragma unroll
        for (int dd4 = 0; dd4 < 4; ++dd4) {
            float4 vv = *(const float4*)&Vs[j*68 + dg + dd4*4];
            oacc[dd4*4+0] = fmaf(p, vv.x, oacc[dd4*4+0]);
            oacc[dd4*4+1] = fmaf(p, vv.y, oacc[dd4*4+1]);
            oacc[dd4*4+2] = fmaf(p, vv.z, oacc[dd4*4+2]);
            oacc[dd4*4+3] = fmaf(p, vv.w, oacc[dd4*4+3]);
        }
    }
    float* obase = out + ((size_t)bh*T_ + qi[r])*D_ + dg;
    #pragma unroll
    for (int dd = 0; dd < 16; ++dd) atomicAdd(obase + dd, oacc[dd]);
    if ((tid & 3) == 0) atomicAdd(den + (size_t)bh*T_ + qi[r], 1.0f);
}

// ---------------------------------------------------------------------------
// K4: out = num / (den + EPS); write aux
// ---------------------------------------------------------------------------
__global__ __launch_bounds__(256)
void k_final(float* __restrict__ out, const float* __restrict__ den,
             const float* __restrict__ aux)
{
    size_t gid = (size_t)blockIdx.x * 256 + threadIdx.x;   // float4 index
    float4* o4 = (float4*)out;
    float d = den[gid >> 4] + 1e-5f;
    float4 x = o4[gid];
    x.x = x.x / d; x.y = x.y / d; x.z = x.z / d; x.w = x.w / d;
    o4[gid] = x;
    if (gid == 0) out[(size_t)BH_*T_*D_] = aux[0] * 1.4901161193847656e-12f; // 1e-4 / (B*H*2T*D)
}

extern "C" void kernel_launch(void* const* d_in, const int* in_sizes, int n_in,
                              void* d_out, int out_size, void* d_ws, size_t ws_size,
                              hipStream_t stream) {
    const float* q     = (const float*)d_in[0];
    const float* k     = (const float*)d_in[1];
    const float* v     = (const float*)d_in[2];
    const float* means = (const float*)d_in[3];
    float* out = (float*)d_out;
    char*  ws  = (char*)d_ws;
    float* aux   = (float*)(ws + OFF_AUX);
    float* den   = (float*)(ws + OFF_DEN);
    int*   qidx  = (int*)(ws + OFF_QIDX);
    int*   kidx  = (int*)(ws + OFF_KIDX);
    float* dists = (float*)(ws + OFF_DISTS);

    hipMemsetAsync(out, 0, (size_t)((size_t)BH_*T_*D_ + 1) * 4, stream);
    hipMemsetAsync(ws, 0, (size_t)OFF_QIDX, stream);   // aux + den

    for (int chunk = 0; chunk < NCHUNK; ++chunk) {
        int bh_base = chunk * CHUNK_BH;
        k_dists<<<dim3(T2_/128, CHUNK_BH), 256, 0, stream>>>(q, k, means, dists, aux, bh_base);
        k_topk <<<dim3(NC_, CHUNK_BH, 2),  256, 0, stream>>>(dists, qidx, kidx, bh_base);
    }
    k_attn<<<dim3(NC_, BH_), 256, 0, stream>>>(q, k, v, qidx, kidx, out, den);
    k_final<<<(BH_*T_*D_/4 + 255)/256, 256, 0, stream>>>(out, den, aux);
}

// Round 2
// 3005.071 us; speedup vs baseline: 1.3989x; 1.3989x over previous
//
#include <hip/hip_runtime.h>
#include <hip/hip_bf16.h>
#include <math.h>

#define B_ 8
#define H_ 8
#define T_ 8192
#define D_ 64
#define NC_ 128
#define WSZ_ 64
#define T2_ (2*T_)
#define BH_ (B_*H_)
#define CHUNK_BH 8
#define NCHUNK (BH_/CHUNK_BH)

// workspace layout (bytes)
#define OFF_AUX   0
#define OFF_DEN   4096
#define OFF_QIDX  (OFF_DEN  + BH_*T_*4)
#define OFF_KIDX  (OFF_QIDX + BH_*NC_*WSZ_*4)
#define OFF_DISTS (OFF_KIDX + BH_*NC_*WSZ_*4)

// ---------------------------------------------------------------------------
// K1: dists (transposed) + argmax + aux partial   (unchanged from round 0)
// ---------------------------------------------------------------------------
__global__ __launch_bounds__(256)
void k_dists(const float* __restrict__ q, const float* __restrict__ k,
             const float* __restrict__ means, float* __restrict__ dists,
             float* __restrict__ aux, int bh_base)
{
    __shared__ float xs[128*64];
    __shared__ float dtile[32*129];
    __shared__ float rno[128];
    __shared__ float ar[4];

    const int tid = threadIdx.x;
    const int bhl = blockIdx.y;
    const int bh  = bh_base + bhl;
    const int h   = bh % H_;
    const int t0  = blockIdx.x * 128;
    const float* mh = means + (size_t)h * NC_ * D_;

    {
        const int lane = tid & 63;
        const int wtok = tid >> 6;
        for (int it = 0; it < 32; ++it) {
            int tl = it*4 + wtok;
            int gt = t0 + tl;
            const float* src = (gt < T_)
                ? (q + ((size_t)bh*T_ + gt)*D_)
                : (k + ((size_t)bh*T_ + (gt - T_))*D_);
            float vv = src[lane];
            xs[tl*64 + lane] = vv;
            float s = vv*vv;
            #pragma unroll
            for (int off = 32; off > 0; off >>= 1) s += __shfl_xor(s, off);
            if (lane == 0) rno[tl] = s;
        }
    }
    __syncthreads();
    if (tid < 128) rno[tid] = fmaxf(sqrtf(rno[tid]), 1e-12f);
    __syncthreads();
    for (int it = 0; it < 32; ++it) {
        int idx = it*256 + tid;
        xs[idx] = xs[idx] / rno[idx >> 6];
    }
    __syncthreads();

    float best = -1e30f; int bestc = 0;
    const int cl = tid & 15;
    const int tg = tid >> 4;
    for (int cbase = 0; cbase < NC_; cbase += 32) {
        const float4* m0p = (const float4*)(mh + (size_t)(cbase + cl)*D_);
        const float4* m1p = (const float4*)(mh + (size_t)(cbase + cl + 16)*D_);
        float acc0[8], acc1[8];
        #pragma unroll
        for (int t = 0; t < 8; ++t) { acc0[t] = 0.f; acc1[t] = 0.f; }
        #pragma unroll 4
        for (int dc = 0; dc < 16; ++dc) {
            float4 m0 = m0p[dc];
            float4 m1 = m1p[dc];
            #pragma unroll
            for (int t = 0; t < 8; ++t) {
                float4 xv = *(const float4*)&xs[(tg*8 + t)*64 + dc*4];
                acc0[t] = fmaf(xv.w, m0.w, fmaf(xv.z, m0.z, fmaf(xv.y, m0.y, fmaf(xv.x, m0.x, acc0[t]))));
                acc1[t] = fmaf(xv.w, m1.w, fmaf(xv.z, m1.z, fmaf(xv.y, m1.y, fmaf(xv.x, m1.x, acc1[t]))));
            }
        }
        #pragma unroll
        for (int t = 0; t < 8; ++t) {
            dtile[cl*129 + tg*8 + t]      = acc0[t];
            dtile[(cl+16)*129 + tg*8 + t] = acc1[t];
        }
        __syncthreads();
        if (tid < 128) {
            #pragma unroll 4
            for (int c = 0; c < 32; ++c) {
                float vv = dtile[c*129 + tid];
                if (vv > best) { best = vv; bestc = cbase + c; }
            }
        }
        {
            const int fc = tid >> 3;
            const int ft = (tid & 7) * 16;
            float* gout = dists + ((size_t)(bhl*NC_ + cbase + fc))*T2_ + t0 + ft;
            #pragma unroll
            for (int j4 = 0; j4 < 4; ++j4) {
                float4 vv;
                vv.x = dtile[fc*129 + ft + j4*4 + 0];
                vv.y = dtile[fc*129 + ft + j4*4 + 1];
                vv.z = dtile[fc*129 + ft + j4*4 + 2];
                vv.w = dtile[fc*129 + ft + j4*4 + 3];
                *(float4*)(gout + j4*4) = vv;
            }
        }
        __syncthreads();
    }

    float asum = 0.f;
    if (tid < 128) {
        const float* mr = mh + (size_t)bestc*D_;
        float s = 0.f;
        for (int j = 0; j < 64; ++j) {
            float dfr = xs[tid*64 + j] - mr[j];
            s = fmaf(dfr, dfr, s);
        }
        asum = s;
    }
    #pragma unroll
    for (int off = 32; off > 0; off >>= 1) asum += __shfl_xor(asum, off);
    if ((tid & 63) == 0) ar[tid >> 6] = asum;
    __syncthreads();
    if (tid == 0) atomicAdd(aux, ar[0] + ar[1] + ar[2] + ar[3]);
}

// ---------------------------------------------------------------------------
// K2: top-64 of 8192 — 1 histogram pass + candidate rank (exact JAX ties).
// ---------------------------------------------------------------------------
__device__ __forceinline__ unsigned flip_f32(float f) {
    unsigned bits = __float_as_uint(f);
    return (bits & 0x80000000u) ? ~bits : (bits | 0x80000000u);
}

__global__ __launch_bounds__(256)
void k_topk(const float* __restrict__ dists, int* __restrict__ qidx,
            int* __restrict__ kidx, int bh_base)
{
    __shared__ unsigned whist[4*256];
    __shared__ unsigned mhist[256];
    __shared__ unsigned cand_u[768];
    __shared__ int      cand_i[768];
    __shared__ int sh[4];   // 0:kk 1:bin 2:nsel 3:ncand

    const int tid   = threadIdx.x;
    const int wid   = tid >> 6;
    const int c     = blockIdx.x;
    const int bhl   = blockIdx.y;
    const int which = blockIdx.z;
    const float* row = dists + ((size_t)(bhl*NC_ + c))*T2_ + (size_t)which*T_;
    int* outp = (which ? kidx : qidx) + ((size_t)((bh_base + bhl)*NC_ + c))*WSZ_;

    for (int i = tid; i < 1024; i += 256) whist[i] = 0;
    if (tid < 4) sh[tid] = 0;
    __syncthreads();

    for (int it = 0; it < 32; ++it) {
        unsigned u = flip_f32(row[it*256 + tid]);
        atomicAdd(&whist[wid*256 + (u >> 24)], 1u);
    }
    __syncthreads();
    if (tid < 256) mhist[tid] = whist[tid] + whist[256+tid] + whist[512+tid] + whist[768+tid];
    __syncthreads();
    if (tid == 0) {
        int kk = WSZ_;
        int b = 255;
        for (; b > 0; --b) {
            int cnt = (int)mhist[b];
            if (kk - cnt <= 0) break;
            kk -= cnt;
        }
        sh[0] = kk; sh[1] = b;
    }
    __syncthreads();
    const int b1 = sh[1];
    const int kk = sh[0];

    for (int it = 0; it < 32; ++it) {
        int i = it*256 + tid;
        unsigned u = flip_f32(row[i]);
        int tb = (int)(u >> 24);
        if (tb > b1) {
            int p = atomicAdd(&sh[2], 1);
            outp[p] = i;
        } else if (tb == b1) {
            int p = atomicAdd(&sh[3], 1);
            if (p < 768) { cand_u[p] = u; cand_i[p] = i; }
        }
    }
    __syncthreads();
    const int G = sh[2];
    const int C = sh[3];

    if (C <= 768) {
        for (int j = tid; j < C; j += 256) {
            unsigned uj = cand_u[j]; int ij = cand_i[j];
            int rank = 0;
            for (int l = 0; l < C; ++l) {
                unsigned ul = cand_u[l];
                rank += (int)((ul > uj) || (ul == uj && cand_i[l] < ij));
            }
            if (rank < kk) outp[G + rank] = ij;
        }
        return;
    }

    // fallback (pathological data): 3 more radix levels + lowest-index ties
    unsigned prefix = ((unsigned)b1) << 24;
    unsigned mask = 0xFF000000u;
    int need = kk;
    for (int shift = 16; shift >= 0; shift -= 8) {
        for (int i = tid; i < 1024; i += 256) whist[i] = 0;
        __syncthreads();
        for (int it = 0; it < 32; ++it) {
            unsigned u = flip_f32(row[it*256 + tid]);
            if ((u & mask) == prefix) atomicAdd(&whist[wid*256 + ((u >> shift) & 255u)], 1u);
        }
        __syncthreads();
        if (tid < 256) mhist[tid] = whist[tid] + whist[256+tid] + whist[512+tid] + whist[768+tid];
        __syncthreads();
        if (tid == 0) {
            int b = 255;
            int k2 = need;
            for (; b > 0; --b) {
                int cnt = (int)mhist[b];
                if (k2 - cnt <= 0) break;
                k2 -= cnt;
            }
            sh[0] = k2; sh[1] = b;
        }
        __syncthreads();
        need = sh[0];
        prefix |= ((unsigned)sh[1]) << shift;
        mask   |= 0xFFu << shift;
        __syncthreads();
    }
    if (tid == 0) sh[3] = 0;
    __syncthreads();
    const unsigned thr = prefix;
    for (int it = 0; it < 32; ++it) {
        int i = it*256 + tid;
        unsigned u = flip_f32(row[i]);
        if (u > thr && (int)(u >> 24) == b1) {
            int p = atomicAdd(&sh[2], 1);
            outp[p] = i;
        } else if (u == thr) {
            int p = atomicAdd(&sh[3], 1);
            if (p < 768) cand_i[p] = i;
        }
    }
    __syncthreads();
    if (tid == 0) {
        int base = sh[2];
        int E = sh[3] < 768 ? sh[3] : 768;
        for (int n = 0; n < need; ++n) {
            int mi = 0x7fffffff, mj = 0;
            for (int j = 0; j < E; ++j) {
                int vv = cand_i[j];
                if (vv < mi) { mi = vv; mj = j; }
            }
            cand_i[mj] = 0x7fffffff;
            outp[base + n] = mi;
        }
    }
}

// ---------------------------------------------------------------------------
// K3: per-cluster 64x64 attention + scatter-add. 4x4 register tiles.
// ---------------------------------------------------------------------------
__global__ __launch_bounds__(256)
void k_attn(const float* __restrict__ q, const float* __restrict__ k,
            const float* __restrict__ v, const int* __restrict__ qidx,
            const int* __restrict__ kidx, float* __restrict__ out,
            float* __restrict__ den)
{
    __shared__ float As[64*68];   // Q, then P (unnormalized e)
    __shared__ float Bs[64*68];   // K, then V
    __shared__ int qi[64], ki[64];

    const int tid = threadIdx.x;
    const int c  = blockIdx.x;
    const int bh = blockIdx.y;
    const int* qp = qidx + ((size_t)(bh*NC_ + c))*WSZ_;
    const int* kp = kidx + ((size_t)(bh*NC_ + c))*WSZ_;
    if (tid < 64) { qi[tid] = qp[tid]; ki[tid] = kp[tid]; }
    __syncthreads();

    const int grow = tid >> 2, gseg = (tid & 3) * 16;
    {
        const float* qsrc = q + ((size_t)bh*T_ + qi[grow])*D_ + gseg;
        const float* ksrc = k + ((size_t)bh*T_ + ki[grow])*D_ + gseg;
        #pragma unroll
        for (int j4 = 0; j4 < 4; ++j4) {
            *(float4*)&As[grow*68 + gseg + j4*4] = ((const float4*)qsrc)[j4];
            *(float4*)&Bs[grow*68 + gseg + j4*4] = ((const float4*)ksrc)[j4];
        }
    }
    __syncthreads();

    const int tx = tid & 15;
    const int ty = tid >> 4;

    float sacc[4][4];
    #pragma unroll
    for (int i = 0; i < 4; ++i)
        #pragma unroll
        for (int j = 0; j < 4; ++j) sacc[i][j] = 0.f;

    for (int kk4 = 0; kk4 < 16; ++kk4) {
        float4 qv[4], kv[4];
        #pragma unroll
        for (int i = 0; i < 4; ++i) qv[i] = *(const float4*)&As[(ty*4+i)*68 + kk4*4];
        #pragma unroll
        for (int j = 0; j < 4; ++j) kv[j] = *(const float4*)&Bs[(tx*4+j)*68 + kk4*4];
        #pragma unroll
        for (int i = 0; i < 4; ++i)
            #pragma unroll
            for (int j = 0; j < 4; ++j)
                sacc[i][j] = fmaf(qv[i].w, kv[j].w, fmaf(qv[i].z, kv[j].z,
                              fmaf(qv[i].y, kv[j].y, fmaf(qv[i].x, kv[j].x, sacc[i][j]))));
    }
    __syncthreads();

    {
        const float* vsrc = v + ((size_t)bh*T_ + ki[grow])*D_ + gseg;
        #pragma unroll
        for (int j4 = 0; j4 < 4; ++j4)
            *(float4*)&Bs[grow*68 + gseg + j4*4] = ((const float4*)vsrc)[j4];
    }

    float rinv[4];
    #pragma unroll
    for (int i = 0; i < 4; ++i) {
        float m = fmaxf(fmaxf(sacc[i][0], sacc[i][1]), fmaxf(sacc[i][2], sacc[i][3]));
        m = fmaxf(m, __shfl_xor(m, 1));
        m = fmaxf(m, __shfl_xor(m, 2));
        m = fmaxf(m, __shfl_xor(m, 4));
        m = fmaxf(m, __shfl_xor(m, 8));
        float4 ev;
        ev.x = expf((sacc[i][0] - m) * 0.125f);
        ev.y = expf((sacc[i][1] - m) * 0.125f);
        ev.z = expf((sacc[i][2] - m) * 0.125f);
        ev.w = expf((sacc[i][3] - m) * 0.125f);
        float s = ev.x + ev.y + ev.z + ev.w;
        s += __shfl_xor(s, 1);
        s += __shfl_xor(s, 2);
        s += __shfl_xor(s, 4);
        s += __shfl_xor(s, 8);
        rinv[i] = 1.0f / s;
        *(float4*)&As[(ty*4+i)*68 + tx*4] = ev;
    }
    __syncthreads();

    float oacc[4][4];
    #pragma unroll
    for (int i = 0; i < 4; ++i)
        #pragma unroll
        for (int j = 0; j < 4; ++j) oacc[i][j] = 0.f;

    for (int jj4 = 0; jj4 < 16; ++jj4) {
        float4 vv[4];
        #pragma unroll
        for (int l = 0; l < 4; ++l) vv[l] = *(const float4*)&Bs[(jj4*4+l)*68 + tx*4];
        #pragma unroll
        for (int i = 0; i < 4; ++i) {
            float4 pv = *(const float4*)&As[(ty*4+i)*68 + jj4*4];
            oacc[i][0] = fmaf(pv.w, vv[3].x, fmaf(pv.z, vv[2].x, fmaf(pv.y, vv[1].x, fmaf(pv.x, vv[0].x, oacc[i][0]))));
            oacc[i][1] = fmaf(pv.w, vv[3].y, fmaf(pv.z, vv[2].y, fmaf(pv.y, vv[1].y, fmaf(pv.x, vv[0].y, oacc[i][1]))));
            oacc[i][2] = fmaf(pv.w, vv[3].z, fmaf(pv.z, vv[2].z, fmaf(pv.y, vv[1].z, fmaf(pv.x, vv[0].z, oacc[i][2]))));
            oacc[i][3] = fmaf(pv.w, vv[3].w, fmaf(pv.z, vv[2].w, fmaf(pv.y, vv[1].w, fmaf(pv.x, vv[0].w, oacc[i][3]))));
        }
    }

    #pragma unroll
    for (int i = 0; i < 4; ++i) {
        const int r = ty*4 + i;
        float* obase = out + ((size_t)bh*T_ + qi[r])*D_ + tx*4;
        #pragma unroll
        for (int j = 0; j < 4; ++j) atomicAdd(obase + j, oacc[i][j] * rinv[i]);
    }
    if (tx == 0) {
        #pragma unroll
        for (int i = 0; i < 4; ++i) atomicAdd(den + (size_t)bh*T_ + qi[ty*4+i], 1.0f);
    }
}

// ---------------------------------------------------------------------------
// K4: out = num / (den + EPS); write aux
// ---------------------------------------------------------------------------
__global__ __launch_bounds__(256)
void k_final(float* __restrict__ out, const float* __restrict__ den,
             const float* __restrict__ aux)
{
    size_t gid = (size_t)blockIdx.x * 256 + threadIdx.x;
    float4* o4 = (float4*)out;
    float d = den[gid >> 4] + 1e-5f;
    float4 x = o4[gid];
    x.x = x.x / d; x.y = x.y / d; x.z = x.z / d; x.w = x.w / d;
    o4[gid] = x;
    if (gid == 0) out[(size_t)BH_*T_*D_] = aux[0] * 1.4901161193847656e-12f;
}

extern "C" void kernel_launch(void* const* d_in, const int* in_sizes, int n_in,
                              void* d_out, int out_size, void* d_ws, size_t ws_size,
                              hipStream_t stream) {
    const float* q     = (const float*)d_in[0];
    const float* k     = (const float*)d_in[1];
    const float* v     = (const float*)d_in[2];
    const float* means = (const float*)d_in[3];
    float* out = (float*)d_out;
    char*  ws  = (char*)d_ws;
    float* aux   = (float*)(ws + OFF_AUX);
    float* den   = (float*)(ws + OFF_DEN);
    int*   qidx  = (int*)(ws + OFF_QIDX);
    int*   kidx  = (int*)(ws + OFF_KIDX);
    float* dists = (float*)(ws + OFF_DISTS);

    hipMemsetAsync(out, 0, (size_t)((size_t)BH_*T_*D_ + 1) * 4, stream);
    hipMemsetAsync(ws, 0, (size_t)OFF_QIDX, stream);

    for (int chunk = 0; chunk < NCHUNK; ++chunk) {
        int bh_base = chunk * CHUNK_BH;
        k_dists<<<dim3(T2_/128, CHUNK_BH), 256, 0, stream>>>(q, k, means, dists, aux, bh_base);
        k_topk <<<dim3(NC_, CHUNK_BH, 2),  256, 0, stream>>>(dists, qidx, kidx, bh_base);
    }
    k_attn<<<dim3(NC_, BH_), 256, 0, stream>>>(q, k, v, qidx, kidx, out, den);
    k_final<<<(BH_*T_*D_/4 + 255)/256, 256, 0, stream>>>(out, den, aux);
}

// Round 3
// 1977.821 us; speedup vs baseline: 2.1255x; 1.5194x over previous
//
#include <hip/hip_runtime.h>
#include <hip/hip_bf16.h>
#include <math.h>

#define B_ 8
#define H_ 8
#define T_ 8192
#define D_ 64
#define NC_ 128
#define WSZ_ 64
#define T2_ (2*T_)
#define BH_ (B_*H_)

// workspace layout (bytes)
#define OFF_AUX    0
#define OFF_DEN    4096
#define OFF_QIDX   (OFF_DEN  + BH_*T_*4)
#define OFF_KIDX   (OFF_QIDX + BH_*NC_*WSZ_*4)
#define OFF_MEANST (OFF_KIDX + BH_*NC_*WSZ_*4)
#define OFF_DISTS  (OFF_MEANST + H_*NC_*D_*4)
// dists: nbh*NC_*T2_ floats, nbh chosen from ws_size (8 MB per bh)

// ---------------------------------------------------------------------------
// K0: transpose means [h][c][d] -> meanst [h][d][c]   (tiny, once)
// ---------------------------------------------------------------------------
__global__ __launch_bounds__(256)
void k_meanst(const float* __restrict__ means, float* __restrict__ meanst)
{
    int gid = blockIdx.x * 256 + threadIdx.x;   // [0, 65536)
    int h = gid >> 13;
    int rem = gid & 8191;
    int d = rem >> 7;
    int c = rem & 127;
    meanst[gid] = means[((h << 7) | c) * 64 + d];
}

// ---------------------------------------------------------------------------
// K1: dists (transposed store) + argmax + aux.  8tok x 8clu register tile.
// grid: (T2/128, nbh)  block: 256
// ---------------------------------------------------------------------------
__global__ __launch_bounds__(256, 4)
void k_dists(const float* __restrict__ q, const float* __restrict__ k,
             const float* __restrict__ means, const float* __restrict__ meanst,
             float* __restrict__ dists, float* __restrict__ aux, int bh_base)
{
    __shared__ float xs[64 * 132];   // [d][token], padded stride 132
    __shared__ int   bcs[128];
    __shared__ float ar[4];

    const int tid = threadIdx.x;
    const int bhl = blockIdx.y;
    const int bh  = bh_base + bhl;
    const int h   = bh % H_;
    const int t0  = blockIdx.x * 128;

    // ---- phase 1: load 128 token rows, normalize, store transposed
    const int lane = tid & 63;
    const int w    = tid >> 6;
    for (int it = 0; it < 32; ++it) {
        int tl = it * 4 + w;
        int gt = t0 + tl;
        const float* src = (gt < T_)
            ? (q + ((size_t)bh * T_ + gt) * D_)
            : (k + ((size_t)bh * T_ + (gt - T_)) * D_);
        float vv = src[lane];
        float s = vv * vv;
        #pragma unroll
        for (int off = 32; off > 0; off >>= 1) s += __shfl_xor(s, off);
        float norm = fmaxf(sqrtf(s), 1e-12f);
        xs[lane * 132 + tl] = vv / norm;
    }
    __syncthreads();

    // ---- phase 2: 8x8 tile per thread over d
    const int ty = tid >> 4;     // token group
    const int tx = tid & 15;     // cluster group
    float acc[8][8];
    #pragma unroll
    for (int i = 0; i < 8; ++i)
        #pragma unroll
        for (int j = 0; j < 8; ++j) acc[i][j] = 0.f;

    const float* mt = meanst + (size_t)h * (64 * 128) + tx * 8;
    #pragma unroll 4
    for (int d = 0; d < 64; ++d) {
        float4 ma = *(const float4*)(mt + d * 128);
        float4 mb = *(const float4*)(mt + d * 128 + 4);
        float4 xa = *(const float4*)&xs[d * 132 + ty * 8];
        float4 xb = *(const float4*)&xs[d * 132 + ty * 8 + 4];
        float xv[8] = {xa.x, xa.y, xa.z, xa.w, xb.x, xb.y, xb.z, xb.w};
        float mv[8] = {ma.x, ma.y, ma.z, ma.w, mb.x, mb.y, mb.z, mb.w};
        #pragma unroll
        for (int i = 0; i < 8; ++i)
            #pragma unroll
            for (int j = 0; j < 8; ++j)
                acc[i][j] = fmaf(xv[i], mv[j], acc[i][j]);
    }

    // ---- phase 3: direct transposed global store
    #pragma unroll
    for (int j = 0; j < 8; ++j) {
        const int c = tx * 8 + j;
        float* gp = dists + ((size_t)(bhl * NC_ + c)) * T2_ + t0 + ty * 8;
        *(float4*)gp       = make_float4(acc[0][j], acc[1][j], acc[2][j], acc[3][j]);
        *(float4*)(gp + 4) = make_float4(acc[4][j], acc[5][j], acc[6][j], acc[7][j]);
    }

    // ---- phase 4: argmax across clusters (16-lane groups share tokens)
    #pragma unroll
    for (int i = 0; i < 8; ++i) {
        float bv = -1e30f; int bcid = 0;
        #pragma unroll
        for (int j = 0; j < 8; ++j) {
            float vv = acc[i][j];
            if (vv > bv) { bv = vv; bcid = tx * 8 + j; }
        }
        #pragma unroll
        for (int off = 1; off < 16; off <<= 1) {
            float ov = __shfl_xor(bv, off);
            int   oc = __shfl_xor(bcid, off);
            if (ov > bv || (ov == bv && oc < bcid)) { bv = ov; bcid = oc; }
        }
        if (tx == 0) bcs[ty * 8 + i] = bcid;
    }
    __syncthreads();

    // ---- phase 5: aux = sum (xn - mean_best)^2
    float part = 0.f;
    for (int it = 0; it < 32; ++it) {
        int tl = it * 4 + w;
        int cb = bcs[tl];
        const float* mr = means + ((size_t)(h * NC_ + cb)) * 64;
        float df = xs[lane * 132 + tl] - mr[lane];
        part = fmaf(df, df, part);
    }
    #pragma unroll
    for (int off = 32; off > 0; off >>= 1) part += __shfl_xor(part, off);
    if (lane == 0) ar[w] = part;
    __syncthreads();
    if (tid == 0) atomicAdd(aux, ar[0] + ar[1] + ar[2] + ar[3]);
}

// ---------------------------------------------------------------------------
// K2: top-64 of 8192 — LDS-staged, 12-bit histogram + exact candidate rank.
// grid: (NC, nbh, 2)  block: 256
// ---------------------------------------------------------------------------
__device__ __forceinline__ unsigned flip_f32(float f) {
    unsigned bits = __float_as_uint(f);
    return (bits & 0x80000000u) ? ~bits : (bits | 0x80000000u);
}

__global__ __launch_bounds__(256)
void k_topk(const float* __restrict__ dists, int* __restrict__ qidx,
            int* __restrict__ kidx, int bh_base)
{
    __shared__ unsigned su[T_];        // 32 KB
    __shared__ unsigned hist[4096];    // 16 KB
    __shared__ unsigned part[256];
    __shared__ unsigned cand_u[768];
    __shared__ int      cand_i[768];
    __shared__ int sh[4];              // 0:kk 1:bin 2:nsel 3:ncand

    const int tid   = threadIdx.x;
    const int c     = blockIdx.x;
    const int bhl   = blockIdx.y;
    const int which = blockIdx.z;
    const float* row = dists + ((size_t)(bhl * NC_ + c)) * T2_ + (size_t)which * T_;
    int* outp = (which ? kidx : qidx) + ((size_t)((bh_base + bhl) * NC_ + c)) * WSZ_;

    for (int i = tid; i < 4096; i += 256) hist[i] = 0;
    if (tid < 4) sh[tid] = 0;
    __syncthreads();

    // pass 1: load+flip into LDS, 12-bit histogram
    for (int it = 0; it < 32; ++it) {
        int i = it * 256 + tid;
        unsigned u = flip_f32(row[i]);
        su[i] = u;
        atomicAdd(&hist[u >> 20], 1u);
    }
    __syncthreads();
    {
        unsigned s = 0;
        #pragma unroll
        for (int j = 0; j < 16; ++j) s += hist[tid * 16 + j];
        part[tid] = s;
    }
    __syncthreads();
    if (tid == 0) {
        int kk = WSZ_;
        int g = 255;
        while (g > 0) {
            int cnt = (int)part[g];
            if (kk - cnt <= 0) break;
            kk -= cnt; --g;
        }
        int b = g * 16 + 15;
        while (b > 0) {
            int cnt = (int)hist[b];
            if (kk - cnt <= 0) break;
            kk -= cnt; --b;
        }
        sh[0] = kk; sh[1] = b;
    }
    __syncthreads();
    const int b1 = sh[1];
    const int kk = sh[0];

    // pass 2: select sure winners, collect threshold-bin candidates
    for (int it = 0; it < 32; ++it) {
        int i = it * 256 + tid;
        unsigned u = su[i];
        int bin = (int)(u >> 20);
        if (bin > b1) {
            int p = atomicAdd(&sh[2], 1);
            outp[p] = i;
        } else if (bin == b1) {
            int p = atomicAdd(&sh[3], 1);
            if (p < 768) { cand_u[p] = u; cand_i[p] = i; }
        }
    }
    __syncthreads();
    const int G = sh[2];
    const int C = sh[3];

    if (C <= 768) {
        // exact rank among candidates: (value desc, index asc)
        for (int j = tid; j < C; j += 256) {
            unsigned uj = cand_u[j]; int ij = cand_i[j];
            int rank = 0;
            for (int l = 0; l < C; ++l) {
                unsigned ul = cand_u[l];
                rank += (int)((ul > uj) || (ul == uj && cand_i[l] < ij));
            }
            if (rank < kk) outp[G + rank] = ij;
        }
        return;
    }

    // ---- fallback (pathological): full 4-level radix over su
    unsigned prefix = 0, mask = 0;
    int need = WSZ_;
    for (int shift = 24; shift >= 0; shift -= 8) {
        if (tid < 256) hist[tid] = 0;
        __syncthreads();
        for (int it = 0; it < 32; ++it) {
            unsigned u = su[it * 256 + tid];
            if ((u & mask) == prefix) atomicAdd(&hist[(u >> shift) & 255u], 1u);
        }
        __syncthreads();
        if (tid == 0) {
            int b = 255;
            int k2 = need;
            while (b > 0) {
                int cnt = (int)hist[b];
                if (k2 - cnt <= 0) break;
                k2 -= cnt; --b;
            }
            sh[0] = k2; sh[1] = b;
        }
        __syncthreads();
        need = sh[0];
        prefix |= ((unsigned)sh[1]) << shift;
        mask   |= 0xFFu << shift;
        __syncthreads();
    }
    if (tid == 0) { sh[2] = 0; sh[3] = 0; }
    __syncthreads();
    const unsigned thr = prefix;
    for (int it = 0; it < 32; ++it) {
        int i = it * 256 + tid;
        unsigned u = su[i];
        if (u > thr) {
            int p = atomicAdd(&sh[2], 1);
            outp[p] = i;
        } else if (u == thr) {
            int p = atomicAdd(&sh[3], 1);
            if (p < 768) cand_i[p] = i;
        }
    }
    __syncthreads();
    if (tid == 0) {
        int base = sh[2];
        int E = sh[3] < 768 ? sh[3] : 768;
        for (int n = 0; n < need; ++n) {
            int mi = 0x7fffffff, mj = 0;
            for (int j = 0; j < E; ++j) {
                int vv = cand_i[j];
                if (vv < mi) { mi = vv; mj = j; }
            }
            cand_i[mj] = 0x7fffffff;
            outp[base + n] = mi;
        }
    }
}

// ---------------------------------------------------------------------------
// K3: per-cluster 64x64 attention + scatter-add. 4x4 register tiles.
// grid: (NC, BH)  block: 256
// ---------------------------------------------------------------------------
__global__ __launch_bounds__(256)
void k_attn(const float* __restrict__ q, const float* __restrict__ k,
            const float* __restrict__ v, const int* __restrict__ qidx,
            const int* __restrict__ kidx, float* __restrict__ out,
            float* __restrict__ den)
{
    __shared__ float As[64 * 68];   // Q, then P (unnormalized e)
    __shared__ float Bs[64 * 68];   // K, then V
    __shared__ int qi[64], ki[64];

    const int tid = threadIdx.x;
    const int c  = blockIdx.x;
    const int bh = blockIdx.y;
    const int* qp = qidx + ((size_t)(bh * NC_ + c)) * WSZ_;
    const int* kp = kidx + ((size_t)(bh * NC_ + c)) * WSZ_;
    if (tid < 64) { qi[tid] = qp[tid]; ki[tid] = kp[tid]; }
    __syncthreads();

    const int grow = tid >> 2, gseg = (tid & 3) * 16;
    {
        const float* qsrc = q + ((size_t)bh * T_ + qi[grow]) * D_ + gseg;
        const float* ksrc = k + ((size_t)bh * T_ + ki[grow]) * D_ + gseg;
        #pragma unroll
        for (int j4 = 0; j4 < 4; ++j4) {
            *(float4*)&As[grow * 68 + gseg + j4 * 4] = ((const float4*)qsrc)[j4];
            *(float4*)&Bs[grow * 68 + gseg + j4 * 4] = ((const float4*)ksrc)[j4];
        }
    }
    __syncthreads();

    const int tx = tid & 15;
    const int ty = tid >> 4;

    float sacc[4][4];
    #pragma unroll
    for (int i = 0; i < 4; ++i)
        #pragma unroll
        for (int j = 0; j < 4; ++j) sacc[i][j] = 0.f;

    for (int kk4 = 0; kk4 < 16; ++kk4) {
        float4 qv[4], kv[4];
        #pragma unroll
        for (int i = 0; i < 4; ++i) qv[i] = *(const float4*)&As[(ty * 4 + i) * 68 + kk4 * 4];
        #pragma unroll
        for (int j = 0; j < 4; ++j) kv[j] = *(const float4*)&Bs[(tx * 4 + j) * 68 + kk4 * 4];
        #pragma unroll
        for (int i = 0; i < 4; ++i)
            #pragma unroll
            for (int j = 0; j < 4; ++j)
                sacc[i][j] = fmaf(qv[i].w, kv[j].w, fmaf(qv[i].z, kv[j].z,
                              fmaf(qv[i].y, kv[j].y, fmaf(qv[i].x, kv[j].x, sacc[i][j]))));
    }
    __syncthreads();

    {
        const float* vsrc = v + ((size_t)bh * T_ + ki[grow]) * D_ + gseg;
        #pragma unroll
        for (int j4 = 0; j4 < 4; ++j4)
            *(float4*)&Bs[grow * 68 + gseg + j4 * 4] = ((const float4*)vsrc)[j4];
    }

    float rinv[4];
    #pragma unroll
    for (int i = 0; i < 4; ++i) {
        float m = fmaxf(fmaxf(sacc[i][0], sacc[i][1]), fmaxf(sacc[i][2], sacc[i][3]));
        m = fmaxf(m, __shfl_xor(m, 1));
        m = fmaxf(m, __shfl_xor(m, 2));
        m = fmaxf(m, __shfl_xor(m, 4));
        m = fmaxf(m, __shfl_xor(m, 8));
        float4 ev;
        ev.x = expf((sacc[i][0] - m) * 0.125f);
        ev.y = expf((sacc[i][1] - m) * 0.125f);
        ev.z = expf((sacc[i][2] - m) * 0.125f);
        ev.w = expf((sacc[i][3] - m) * 0.125f);
        float s = ev.x + ev.y + ev.z + ev.w;
        s += __shfl_xor(s, 1);
        s += __shfl_xor(s, 2);
        s += __shfl_xor(s, 4);
        s += __shfl_xor(s, 8);
        rinv[i] = 1.0f / s;
        *(float4*)&As[(ty * 4 + i) * 68 + tx * 4] = ev;
    }
    __syncthreads();

    float oacc[4][4];
    #pragma unroll
    for (int i = 0; i < 4; ++i)
        #pragma unroll
        for (int j = 0; j < 4; ++j) oacc[i][j] = 0.f;

    for (int jj4 = 0; jj4 < 16; ++jj4) {
        float4 vv[4];
        #pragma unroll
        for (int l = 0; l < 4; ++l) vv[l] = *(const float4*)&Bs[(jj4 * 4 + l) * 68 + tx * 4];
        #pragma unroll
        for (int i = 0; i < 4; ++i) {
            float4 pv = *(const float4*)&As[(ty * 4 + i) * 68 + jj4 * 4];
            oacc[i][0] = fmaf(pv.w, vv[3].x, fmaf(pv.z, vv[2].x, fmaf(pv.y, vv[1].x, fmaf(pv.x, vv[0].x, oacc[i][0]))));
            oacc[i][1] = fmaf(pv.w, vv[3].y, fmaf(pv.z, vv[2].y, fmaf(pv.y, vv[1].y, fmaf(pv.x, vv[0].y, oacc[i][1]))));
            oacc[i][2] = fmaf(pv.w, vv[3].z, fmaf(pv.z, vv[2].z, fmaf(pv.y, vv[1].z, fmaf(pv.x, vv[0].z, oacc[i][2]))));
            oacc[i][3] = fmaf(pv.w, vv[3].w, fmaf(pv.z, vv[2].w, fmaf(pv.y, vv[1].w, fmaf(pv.x, vv[0].w, oacc[i][3]))));
        }
    }

    #pragma unroll
    for (int i = 0; i < 4; ++i) {
        const int r = ty * 4 + i;
        float* obase = out + ((size_t)bh * T_ + qi[r]) * D_ + tx * 4;
        #pragma unroll
        for (int j = 0; j < 4; ++j) atomicAdd(obase + j, oacc[i][j] * rinv[i]);
    }
    if (tx == 0) {
        #pragma unroll
        for (int i = 0; i < 4; ++i) atomicAdd(den + (size_t)bh * T_ + qi[ty * 4 + i], 1.0f);
    }
}

// ---------------------------------------------------------------------------
// K4: out = num / (den + EPS); write aux
// ---------------------------------------------------------------------------
__global__ __launch_bounds__(256)
void k_final(float* __restrict__ out, const float* __restrict__ den,
             const float* __restrict__ aux)
{
    size_t gid = (size_t)blockIdx.x * 256 + threadIdx.x;
    float4* o4 = (float4*)out;
    float d = den[gid >> 4] + 1e-5f;
    float4 x = o4[gid];
    x.x = x.x / d; x.y = x.y / d; x.z = x.z / d; x.w = x.w / d;
    o4[gid] = x;
    if (gid == 0) out[(size_t)BH_ * T_ * D_] = aux[0] * 1.4901161193847656e-12f;
}

extern "C" void kernel_launch(void* const* d_in, const int* in_sizes, int n_in,
                              void* d_out, int out_size, void* d_ws, size_t ws_size,
                              hipStream_t stream) {
    const float* q     = (const float*)d_in[0];
    const float* k     = (const float*)d_in[1];
    const float* v     = (const float*)d_in[2];
    const float* means = (const float*)d_in[3];
    float* out = (float*)d_out;
    char*  ws  = (char*)d_ws;
    float* aux    = (float*)(ws + OFF_AUX);
    float* den    = (float*)(ws + OFF_DEN);
    int*   qidx   = (int*)(ws + OFF_QIDX);
    int*   kidx   = (int*)(ws + OFF_KIDX);
    float* meanst = (float*)(ws + OFF_MEANST);
    float* dists  = (float*)(ws + OFF_DISTS);

    hipMemsetAsync(out, 0, (size_t)((size_t)BH_ * T_ * D_ + 1) * 4, stream);
    hipMemsetAsync(ws, 0, (size_t)OFF_QIDX, stream);   // aux + den

    k_meanst<<<256, 256, 0, stream>>>(means, meanst);

    // adaptive chunking over bh based on available workspace
    size_t per_bh = (size_t)NC_ * T2_ * 4;   // 8 MB
    int nbh = 1;
    if (ws_size > OFF_DISTS) {
        size_t fit = (ws_size - OFF_DISTS) / per_bh;
        nbh = (fit < 1) ? 1 : (fit > BH_ ? BH_ : (int)fit);
    }

    for (int bh_base = 0; bh_base < BH_; bh_base += nbh) {
        int cur = BH_ - bh_base < nbh ? BH_ - bh_base : nbh;
        k_dists<<<dim3(T2_ / 128, cur), 256, 0, stream>>>(q, k, means, meanst, dists, aux, bh_base);
        k_topk <<<dim3(NC_, cur, 2),    256, 0, stream>>>(dists, qidx, kidx, bh_base);
    }
    k_attn<<<dim3(NC_, BH_), 256, 0, stream>>>(q, k, v, qidx, kidx, out, den);
    k_final<<<(BH_ * T_ * D_ / 4 + 255) / 256, 256, 0, stream>>>(out, den, aux);
}

// Round 4
// 1316.822 us; speedup vs baseline: 3.1924x; 1.5020x over previous
//
#include <hip/hip_runtime.h>
#include <hip/hip_bf16.h>
#include <math.h>

#define B_ 8
#define H_ 8
#define T_ 8192
#define D_ 64
#define NC_ 128
#define WSZ_ 64
#define T2_ (2*T_)
#define BH_ (B_*H_)

// workspace layout (bytes)
#define OFF_AUX    0
#define OFF_DEN    4096
#define OFF_QIDX   (OFF_DEN  + BH_*T_*4)
#define OFF_KIDX   (OFF_QIDX + BH_*NC_*WSZ_*4)
#define OFF_MEANST (OFF_KIDX + BH_*NC_*WSZ_*4)
#define OFF_DISTS  (OFF_MEANST + H_*NC_*D_*4)
// dists: nbh*NC_*T2_ floats, nbh chosen from ws_size (8 MB per bh)

// ---------------------------------------------------------------------------
// K0: transpose means [h][c][d] -> meanst [h][d][c]   (tiny, once)
// ---------------------------------------------------------------------------
__global__ __launch_bounds__(256)
void k_meanst(const float* __restrict__ means, float* __restrict__ meanst)
{
    int gid = blockIdx.x * 256 + threadIdx.x;   // [0, 65536)
    int h = gid >> 13;
    int rem = gid & 8191;
    int d = rem >> 7;
    int c = rem & 127;
    meanst[gid] = means[((h << 7) | c) * 64 + d];
}

// ---------------------------------------------------------------------------
// K1: dists (transposed store) + argmax + aux.  8tok x 8clu register tile.
// grid: (T2/128, nbh)  block: 256
// ---------------------------------------------------------------------------
__global__ __launch_bounds__(256, 4)
void k_dists(const float* __restrict__ q, const float* __restrict__ k,
             const float* __restrict__ means, const float* __restrict__ meanst,
             float* __restrict__ dists, float* __restrict__ aux, int bh_base)
{
    __shared__ float xs[64 * 132];   // [d][token], padded stride 132
    __shared__ int   bcs[128];
    __shared__ float ar[4];

    const int tid = threadIdx.x;
    const int bhl = blockIdx.y;
    const int bh  = bh_base + bhl;
    const int h   = bh % H_;
    const int t0  = blockIdx.x * 128;

    // ---- phase 1: load 128 token rows, normalize, store transposed
    const int lane = tid & 63;
    const int w    = tid >> 6;
    for (int it = 0; it < 32; ++it) {
        int tl = it * 4 + w;
        int gt = t0 + tl;
        const float* src = (gt < T_)
            ? (q + ((size_t)bh * T_ + gt) * D_)
            : (k + ((size_t)bh * T_ + (gt - T_)) * D_);
        float vv = src[lane];
        float s = vv * vv;
        #pragma unroll
        for (int off = 32; off > 0; off >>= 1) s += __shfl_xor(s, off);
        float norm = fmaxf(sqrtf(s), 1e-12f);
        xs[lane * 132 + tl] = vv / norm;
    }
    __syncthreads();

    // ---- phase 2: 8x8 tile per thread over d
    const int ty = tid >> 4;     // token group
    const int tx = tid & 15;     // cluster group
    float acc[8][8];
    #pragma unroll
    for (int i = 0; i < 8; ++i)
        #pragma unroll
        for (int j = 0; j < 8; ++j) acc[i][j] = 0.f;

    const float* mt = meanst + (size_t)h * (64 * 128) + tx * 8;
    #pragma unroll 4
    for (int d = 0; d < 64; ++d) {
        float4 ma = *(const float4*)(mt + d * 128);
        float4 mb = *(const float4*)(mt + d * 128 + 4);
        float4 xa = *(const float4*)&xs[d * 132 + ty * 8];
        float4 xb = *(const float4*)&xs[d * 132 + ty * 8 + 4];
        float xv[8] = {xa.x, xa.y, xa.z, xa.w, xb.x, xb.y, xb.z, xb.w};
        float mv[8] = {ma.x, ma.y, ma.z, ma.w, mb.x, mb.y, mb.z, mb.w};
        #pragma unroll
        for (int i = 0; i < 8; ++i)
            #pragma unroll
            for (int j = 0; j < 8; ++j)
                acc[i][j] = fmaf(xv[i], mv[j], acc[i][j]);
    }

    // ---- phase 3: direct transposed global store
    #pragma unroll
    for (int j = 0; j < 8; ++j) {
        const int c = tx * 8 + j;
        float* gp = dists + ((size_t)(bhl * NC_ + c)) * T2_ + t0 + ty * 8;
        *(float4*)gp       = make_float4(acc[0][j], acc[1][j], acc[2][j], acc[3][j]);
        *(float4*)(gp + 4) = make_float4(acc[4][j], acc[5][j], acc[6][j], acc[7][j]);
    }

    // ---- phase 4: argmax across clusters (16-lane groups share tokens)
    #pragma unroll
    for (int i = 0; i < 8; ++i) {
        float bv = -1e30f; int bcid = 0;
        #pragma unroll
        for (int j = 0; j < 8; ++j) {
            float vv = acc[i][j];
            if (vv > bv) { bv = vv; bcid = tx * 8 + j; }
        }
        #pragma unroll
        for (int off = 1; off < 16; off <<= 1) {
            float ov = __shfl_xor(bv, off);
            int   oc = __shfl_xor(bcid, off);
            if (ov > bv || (ov == bv && oc < bcid)) { bv = ov; bcid = oc; }
        }
        if (tx == 0) bcs[ty * 8 + i] = bcid;
    }
    __syncthreads();

    // ---- phase 5: aux = sum (xn - mean_best)^2
    float part = 0.f;
    for (int it = 0; it < 32; ++it) {
        int tl = it * 4 + w;
        int cb = bcs[tl];
        const float* mr = means + ((size_t)(h * NC_ + cb)) * 64;
        float df = xs[lane * 132 + tl] - mr[lane];
        part = fmaf(df, df, part);
    }
    #pragma unroll
    for (int off = 32; off > 0; off >>= 1) part += __shfl_xor(part, off);
    if (lane == 0) ar[w] = part;
    __syncthreads();
    if (tid == 0) atomicAdd(aux, ar[0] + ar[1] + ar[2] + ar[3]);
}

// ---------------------------------------------------------------------------
// K2 v4: top-64 of 8192 — register-resident values, 12-bit histogram,
// parallel suffix-scan threshold search, exact candidate rank (JAX ties).
// grid: (NC, nbh, 2)  block: 256
// ---------------------------------------------------------------------------
__device__ __forceinline__ unsigned flip_f32(float f) {
    unsigned bits = __float_as_uint(f);
    return (bits & 0x80000000u) ? ~bits : (bits | 0x80000000u);
}

__global__ __launch_bounds__(256)
void k_topk(const float* __restrict__ dists, int* __restrict__ qidx,
            int* __restrict__ kidx, int bh_base)
{
    __shared__ unsigned hist[4096];    // 16 KB
    __shared__ unsigned sfx[256];
    __shared__ unsigned wtot[4];
    __shared__ unsigned cand_u[768];
    __shared__ int      cand_i[768];
    __shared__ int sh[6];   // 0:g1 1:b1 2:nsel 3:ncand 4:kk

    const int tid   = threadIdx.x;
    const int c     = blockIdx.x;
    const int bhl   = blockIdx.y;
    const int which = blockIdx.z;
    const float* row = dists + ((size_t)(bhl * NC_ + c)) * T2_ + (size_t)which * T_;
    int* outp = (which ? kidx : qidx) + ((size_t)((bh_base + bhl) * NC_ + c)) * WSZ_;

    // ---- load 32 values into registers (coalesced float4), flip to orderable u32
    unsigned u[32];
    {
        const float4* r4 = (const float4*)row;
        #pragma unroll
        for (int it = 0; it < 8; ++it) {
            float4 f = r4[it * 256 + tid];
            u[it * 4 + 0] = flip_f32(f.x);
            u[it * 4 + 1] = flip_f32(f.y);
            u[it * 4 + 2] = flip_f32(f.z);
            u[it * 4 + 3] = flip_f32(f.w);
        }
    }
    for (int i = tid; i < 4096; i += 256) hist[i] = 0;
    if (tid < 6) sh[tid] = (tid < 2) ? -1 : 0;
    __syncthreads();

    // ---- 12-bit histogram
    #pragma unroll
    for (int j = 0; j < 32; ++j) atomicAdd(&hist[u[j] >> 20], 1u);
    __syncthreads();

    // ---- group sums (16 bins/group) + wave suffix scan -> sfx[g] = count(bins >= g*16)
    unsigned gs = 0;
    #pragma unroll
    for (int j = 0; j < 16; ++j) gs += hist[tid * 16 + j];

    const int l = tid & 63, w = tid >> 6;
    unsigned sv = gs;
    #pragma unroll
    for (int off = 1; off < 64; off <<= 1) {
        unsigned up = __shfl_down(sv, off);
        if (l + off < 64) sv += up;
    }
    if (l == 0) wtot[w] = sv;
    __syncthreads();
    unsigned hi = 0;
    for (int ww = w + 1; ww < 4; ++ww) hi += wtot[ww];
    unsigned suffix = sv + hi;
    sfx[tid] = suffix;
    if (suffix >= WSZ_) atomicMax(&sh[0], tid);
    __syncthreads();
    const int g1 = sh[0];
    const unsigned above_groups = (g1 < 255) ? sfx[g1 + 1] : 0u;

    // ---- bin-level refine within group g1 (16 threads, <=16 adds each)
    if (tid < 16) {
        unsigned bs = above_groups;
        for (int j = 15; j >= tid; --j) bs += hist[g1 * 16 + j];
        if (bs >= WSZ_) atomicMax(&sh[1], g1 * 16 + tid);
    }
    __syncthreads();
    const int b1 = sh[1];
    if (tid == 0) {
        unsigned gt = above_groups;
        for (int j = b1 + 1; j <= g1 * 16 + 15; ++j) gt += hist[j];
        sh[4] = WSZ_ - (int)gt;    // how many to take from bin b1
    }
    __syncthreads();
    const int kk = sh[4];

    // ---- selection from registers
    #pragma unroll
    for (int j = 0; j < 32; ++j) {
        int bin = (int)(u[j] >> 20);
        int idx = (j >> 2) * 1024 + tid * 4 + (j & 3);
        if (bin > b1) {
            int p = atomicAdd(&sh[2], 1);
            outp[p] = idx;
        } else if (bin == b1) {
            int p = atomicAdd(&sh[3], 1);
            if (p < 768) { cand_u[p] = u[j]; cand_i[p] = idx; }
        }
    }
    __syncthreads();
    const int G = sh[2];
    const int C = sh[3];

    if (C <= 768) {
        // exact rank among candidates: (value desc, index asc)
        for (int j = tid; j < C; j += 256) {
            unsigned uj = cand_u[j]; int ij = cand_i[j];
            int rank = 0;
            for (int ll = 0; ll < C; ++ll) {
                unsigned ul = cand_u[ll];
                rank += (int)((ul > uj) || (ul == uj && cand_i[ll] < ij));
            }
            if (rank < kk) outp[G + rank] = ij;
        }
        return;
    }

    // ---- fallback (pathological): full 4-level radix re-reading global
    unsigned prefix = 0, mask = 0;
    int need = WSZ_;
    for (int shift = 24; shift >= 0; shift -= 8) {
        if (tid < 256) hist[tid] = 0;
        __syncthreads();
        for (int it = 0; it < 32; ++it) {
            unsigned uu = flip_f32(row[it * 256 + tid]);
            if ((uu & mask) == prefix) atomicAdd(&hist[(uu >> shift) & 255u], 1u);
        }
        __syncthreads();
        if (tid == 0) {
            int b = 255;
            int k2 = need;
            while (b > 0) {
                int cnt = (int)hist[b];
                if (k2 - cnt <= 0) break;
                k2 -= cnt; --b;
            }
            sh[0] = k2; sh[1] = b;
        }
        __syncthreads();
        need = sh[0];
        prefix |= ((unsigned)sh[1]) << shift;
        mask   |= 0xFFu << shift;
        __syncthreads();
    }
    if (tid == 0) { sh[2] = 0; sh[3] = 0; }
    __syncthreads();
    const unsigned thr = prefix;
    for (int it = 0; it < 32; ++it) {
        int i = it * 256 + tid;
        unsigned uu = flip_f32(row[i]);
        if (uu > thr) {
            int p = atomicAdd(&sh[2], 1);
            outp[p] = i;
        } else if (uu == thr) {
            int p = atomicAdd(&sh[3], 1);
            if (p < 768) cand_i[p] = i;
        }
    }
    __syncthreads();
    if (tid == 0) {
        int base = sh[2];
        int E = sh[3] < 768 ? sh[3] : 768;
        for (int n = 0; n < need; ++n) {
            int mi = 0x7fffffff, mj = 0;
            for (int j = 0; j < E; ++j) {
                int vv = cand_i[j];
                if (vv < mi) { mi = vv; mj = j; }
            }
            cand_i[mj] = 0x7fffffff;
            outp[base + n] = mi;
        }
    }
}

// ---------------------------------------------------------------------------
// K3: per-cluster 64x64 attention + scatter-add. 4x4 register tiles.
// grid: (NC, BH)  block: 256
// ---------------------------------------------------------------------------
__global__ __launch_bounds__(256)
void k_attn(const float* __restrict__ q, const float* __restrict__ k,
            const float* __restrict__ v, const int* __restrict__ qidx,
            const int* __restrict__ kidx, float* __restrict__ out,
            float* __restrict__ den)
{
    __shared__ float As[64 * 68];   // Q, then P (unnormalized e)
    __shared__ float Bs[64 * 68];   // K, then V
    __shared__ int qi[64], ki[64];

    const int tid = threadIdx.x;
    const int c  = blockIdx.x;
    const int bh = blockIdx.y;
    const int* qp = qidx + ((size_t)(bh * NC_ + c)) * WSZ_;
    const int* kp = kidx + ((size_t)(bh * NC_ + c)) * WSZ_;
    if (tid < 64) { qi[tid] = qp[tid]; ki[tid] = kp[tid]; }
    __syncthreads();

    const int grow = tid >> 2, gseg = (tid & 3) * 16;
    {
        const float* qsrc = q + ((size_t)bh * T_ + qi[grow]) * D_ + gseg;
        const float* ksrc = k + ((size_t)bh * T_ + ki[grow]) * D_ + gseg;
        #pragma unroll
        for (int j4 = 0; j4 < 4; ++j4) {
            *(float4*)&As[grow * 68 + gseg + j4 * 4] = ((const float4*)qsrc)[j4];
            *(float4*)&Bs[grow * 68 + gseg + j4 * 4] = ((const float4*)ksrc)[j4];
        }
    }
    __syncthreads();

    const int tx = tid & 15;
    const int ty = tid >> 4;

    float sacc[4][4];
    #pragma unroll
    for (int i = 0; i < 4; ++i)
        #pragma unroll
        for (int j = 0; j < 4; ++j) sacc[i][j] = 0.f;

    for (int kk4 = 0; kk4 < 16; ++kk4) {
        float4 qv[4], kv[4];
        #pragma unroll
        for (int i = 0; i < 4; ++i) qv[i] = *(const float4*)&As[(ty * 4 + i) * 68 + kk4 * 4];
        #pragma unroll
        for (int j = 0; j < 4; ++j) kv[j] = *(const float4*)&Bs[(tx * 4 + j) * 68 + kk4 * 4];
        #pragma unroll
        for (int i = 0; i < 4; ++i)
            #pragma unroll
            for (int j = 0; j < 4; ++j)
                sacc[i][j] = fmaf(qv[i].w, kv[j].w, fmaf(qv[i].z, kv[j].z,
                              fmaf(qv[i].y, kv[j].y, fmaf(qv[i].x, kv[j].x, sacc[i][j]))));
    }
    __syncthreads();

    {
        const float* vsrc = v + ((size_t)bh * T_ + ki[grow]) * D_ + gseg;
        #pragma unroll
        for (int j4 = 0; j4 < 4; ++j4)
            *(float4*)&Bs[grow * 68 + gseg + j4 * 4] = ((const float4*)vsrc)[j4];
    }

    float rinv[4];
    #pragma unroll
    for (int i = 0; i < 4; ++i) {
        float m = fmaxf(fmaxf(sacc[i][0], sacc[i][1]), fmaxf(sacc[i][2], sacc[i][3]));
        m = fmaxf(m, __shfl_xor(m, 1));
        m = fmaxf(m, __shfl_xor(m, 2));
        m = fmaxf(m, __shfl_xor(m, 4));
        m = fmaxf(m, __shfl_xor(m, 8));
        float4 ev;
        ev.x = expf((sacc[i][0] - m) * 0.125f);
        ev.y = expf((sacc[i][1] - m) * 0.125f);
        ev.z = expf((sacc[i][2] - m) * 0.125f);
        ev.w = expf((sacc[i][3] - m) * 0.125f);
        float s = ev.x + ev.y + ev.z + ev.w;
        s += __shfl_xor(s, 1);
        s += __shfl_xor(s, 2);
        s += __shfl_xor(s, 4);
        s += __shfl_xor(s, 8);
        rinv[i] = 1.0f / s;
        *(float4*)&As[(ty * 4 + i) * 68 + tx * 4] = ev;
    }
    __syncthreads();

    float oacc[4][4];
    #pragma unroll
    for (int i = 0; i < 4; ++i)
        #pragma unroll
        for (int j = 0; j < 4; ++j) oacc[i][j] = 0.f;

    for (int jj4 = 0; jj4 < 16; ++jj4) {
        float4 vv[4];
        #pragma unroll
        for (int ll = 0; ll < 4; ++ll) vv[ll] = *(const float4*)&Bs[(jj4 * 4 + ll) * 68 + tx * 4];
        #pragma unroll
        for (int i = 0; i < 4; ++i) {
            float4 pv = *(const float4*)&As[(ty * 4 + i) * 68 + jj4 * 4];
            oacc[i][0] = fmaf(pv.w, vv[3].x, fmaf(pv.z, vv[2].x, fmaf(pv.y, vv[1].x, fmaf(pv.x, vv[0].x, oacc[i][0]))));
            oacc[i][1] = fmaf(pv.w, vv[3].y, fmaf(pv.z, vv[2].y, fmaf(pv.y, vv[1].y, fmaf(pv.x, vv[0].y, oacc[i][1]))));
            oacc[i][2] = fmaf(pv.w, vv[3].z, fmaf(pv.z, vv[2].z, fmaf(pv.y, vv[1].z, fmaf(pv.x, vv[0].z, oacc[i][2]))));
            oacc[i][3] = fmaf(pv.w, vv[3].w, fmaf(pv.z, vv[2].w, fmaf(pv.y, vv[1].w, fmaf(pv.x, vv[0].w, oacc[i][3]))));
        }
    }

    #pragma unroll
    for (int i = 0; i < 4; ++i) {
        const int r = ty * 4 + i;
        float* obase = out + ((size_t)bh * T_ + qi[r]) * D_ + tx * 4;
        #pragma unroll
        for (int j = 0; j < 4; ++j) atomicAdd(obase + j, oacc[i][j] * rinv[i]);
    }
    if (tx == 0) {
        #pragma unroll
        for (int i = 0; i < 4; ++i) atomicAdd(den + (size_t)bh * T_ + qi[ty * 4 + i], 1.0f);
    }
}

// ---------------------------------------------------------------------------
// K4: out = num / (den + EPS); write aux
// ---------------------------------------------------------------------------
__global__ __launch_bounds__(256)
void k_final(float* __restrict__ out, const float* __restrict__ den,
             const float* __restrict__ aux)
{
    size_t gid = (size_t)blockIdx.x * 256 + threadIdx.x;
    float4* o4 = (float4*)out;
    float d = den[gid >> 4] + 1e-5f;
    float4 x = o4[gid];
    x.x = x.x / d; x.y = x.y / d; x.z = x.z / d; x.w = x.w / d;
    o4[gid] = x;
    if (gid == 0) out[(size_t)BH_ * T_ * D_] = aux[0] * 1.4901161193847656e-12f;
}

extern "C" void kernel_launch(void* const* d_in, const int* in_sizes, int n_in,
                              void* d_out, int out_size, void* d_ws, size_t ws_size,
                              hipStream_t stream) {
    const float* q     = (const float*)d_in[0];
    const float* k     = (const float*)d_in[1];
    const float* v     = (const float*)d_in[2];
    const float* means = (const float*)d_in[3];
    float* out = (float*)d_out;
    char*  ws  = (char*)d_ws;
    float* aux    = (float*)(ws + OFF_AUX);
    float* den    = (float*)(ws + OFF_DEN);
    int*   qidx   = (int*)(ws + OFF_QIDX);
    int*   kidx   = (int*)(ws + OFF_KIDX);
    float* meanst = (float*)(ws + OFF_MEANST);
    float* dists  = (float*)(ws + OFF_DISTS);

    hipMemsetAsync(out, 0, (size_t)((size_t)BH_ * T_ * D_ + 1) * 4, stream);
    hipMemsetAsync(ws, 0, (size_t)OFF_QIDX, stream);   // aux + den

    k_meanst<<<256, 256, 0, stream>>>(means, meanst);

    // adaptive chunking over bh based on available workspace
    size_t per_bh = (size_t)NC_ * T2_ * 4;   // 8 MB
    int nbh = 1;
    if (ws_size > OFF_DISTS) {
        size_t fit = (ws_size - OFF_DISTS) / per_bh;
        nbh = (fit < 1) ? 1 : (fit > BH_ ? BH_ : (int)fit);
    }

    for (int bh_base = 0; bh_base < BH_; bh_base += nbh) {
        int cur = BH_ - bh_base < nbh ? BH_ - bh_base : nbh;
        k_dists<<<dim3(T2_ / 128, cur), 256, 0, stream>>>(q, k, means, meanst, dists, aux, bh_base);
        k_topk <<<dim3(NC_, cur, 2),    256, 0, stream>>>(dists, qidx, kidx, bh_base);
    }
    k_attn<<<dim3(NC_, BH_), 256, 0, stream>>>(q, k, v, qidx, kidx, out, den);
    k_final<<<(BH_ * T_ * D_ / 4 + 255) / 256, 256, 0, stream>>>(out, den, aux);
}